// Round 7
// baseline (208.002 us; speedup 1.0000x reference)
//
#include <hip/hip_runtime.h>
#include <math.h>

// Problem constants (reference: N=200000, D=256, 2 heads, 2 att iters)
#define NROWS 200000
#define D 256
#define F4 64          // float4 per row

// Grid: 1250 blocks x 160 rows = 200000 exactly.
// Block = 4 waves; wave = 4 consecutive rows per iter, 10 iters, depth-2 prefetch.
#define NBLK 1250
#define CHUNK 160
#define ITERS 10

// Workspace layout (floats). No atomics -> no zeroing.
#define WS_H1 0          // 512   per-head h1
#define WS_H2 512        // 512   per-head h2
#define WS_A  1024       // 2*N   a1 per row (head0 then head1)
#define WS_P1 401024     // 1250*256 colsum partials
#define WS_P2 721024     // 1250*512 pass partials

__device__ __forceinline__ float att_sigmoid(float s) {
    float t = s / fmaxf(fabsf(s), 1e-12f);
    return 1.0f / (1.0f + __expf(-t));
}

__device__ __forceinline__ float wave_sum(float v) {
#pragma unroll
    for (int off = 1; off < 64; off <<= 1) v += __shfl_xor(v, off);
    return v;
}

__device__ __forceinline__ float dot4(float4 a, float4 b) {
    return fmaf(a.x, b.x, fmaf(a.y, b.y, fmaf(a.z, b.z, a.w * b.w)));
}

__device__ __forceinline__ void acc4(float4& acc, float s, const float4& v) {
    acc.x = fmaf(s, v.x, acc.x);
    acc.y = fmaf(s, v.y, acc.y);
    acc.z = fmaf(s, v.z, acc.z);
    acc.w = fmaf(s, v.w, acc.w);
}

// ---- colsum: per-block partial column sums (depth-2 prefetch) ----
__global__ void __launch_bounds__(256, 4) colsum_kernel(const float* __restrict__ x,
                                                        float* __restrict__ part) {
    const int tid = threadIdx.x, lane = tid & 63, wv = tid >> 6;
    const float4* x4 = reinterpret_cast<const float4*>(x);
    const size_t base = (size_t)(blockIdx.x * CHUNK + wv * 4) * F4 + lane;
    float4 b0[4], b1[4], b2[4];
#pragma unroll
    for (int j = 0; j < 4; ++j) b0[j] = x4[base + j * F4];
#pragma unroll
    for (int j = 0; j < 4; ++j) b1[j] = x4[base + 16 * F4 + j * F4];
    float4 accA = make_float4(0.f, 0.f, 0.f, 0.f);
    float4 accB = make_float4(0.f, 0.f, 0.f, 0.f);
    for (int it = 0; it < ITERS; ++it) {
        if (it + 2 < ITERS) {
            const size_t nb = base + (size_t)(it + 2) * 16 * F4;
#pragma unroll
            for (int j = 0; j < 4; ++j) b2[j] = x4[nb + j * F4];
        }
        accA.x += b0[0].x + b0[1].x; accB.x += b0[2].x + b0[3].x;
        accA.y += b0[0].y + b0[1].y; accB.y += b0[2].y + b0[3].y;
        accA.z += b0[0].z + b0[1].z; accB.z += b0[2].z + b0[3].z;
        accA.w += b0[0].w + b0[1].w; accB.w += b0[2].w + b0[3].w;
#pragma unroll
        for (int j = 0; j < 4; ++j) { b0[j] = b1[j]; b1[j] = b2[j]; }
    }
    accA.x += accB.x; accA.y += accB.y; accA.z += accB.z; accA.w += accB.w;
    __shared__ float4 sh[256];
    sh[tid] = accA;
    __syncthreads();
    if (tid < 64) {
        float4 a = sh[tid], b = sh[tid + 64], c = sh[tid + 128], d = sh[tid + 192];
        float4 s;
        s.x = (a.x + b.x) + (c.x + d.x);
        s.y = (a.y + b.y) + (c.y + d.y);
        s.z = (a.z + b.z) + (c.z + d.z);
        s.w = (a.w + b.w) + (c.w + d.w);
        reinterpret_cast<float4*>(part)[blockIdx.x * 64 + tid] = s;
    }
}

// ---- fused: reduce NBLK partial rows -> v, then h = tanh((v*scale) @ W) ----
__global__ void __launch_bounds__(256) hproj_fused(const float* __restrict__ W,
                                                   const float* __restrict__ part,
                                                   int width4, int headOff4, float scale,
                                                   float* __restrict__ hout) {
    const int head = blockIdx.x;
    const int tid = threadIdx.x, lane = tid & 63, wv = tid >> 6;
    const float4* p4 = reinterpret_cast<const float4*>(part) + head * headOff4 + lane;
    float4 s = make_float4(0.f, 0.f, 0.f, 0.f);
#pragma unroll 5
    for (int r = wv; r < NBLK; r += 4) {
        float4 v = p4[(size_t)r * width4];
        s.x += v.x; s.y += v.y; s.z += v.z; s.w += v.w;
    }
    __shared__ float4 red[4][64];
    __shared__ float vbuf[D];
    red[wv][lane] = s;
    __syncthreads();
    if (tid < 64) {
        float4 a = red[0][tid], b = red[1][tid], c = red[2][tid], d = red[3][tid];
        vbuf[tid * 4 + 0] = ((a.x + b.x) + (c.x + d.x)) * scale;
        vbuf[tid * 4 + 1] = ((a.y + b.y) + (c.y + d.y)) * scale;
        vbuf[tid * 4 + 2] = ((a.z + b.z) + (c.z + d.z)) * scale;
        vbuf[tid * 4 + 3] = ((a.w + b.w) + (c.w + d.w)) * scale;
    }
    __syncthreads();
    const float* Wh = W + head * D * D;
    float acc = 0.0f;
#pragma unroll 8
    for (int k = 0; k < D; ++k) acc = fmaf(vbuf[k], Wh[k * D + tid], acc);
    hout[head * D + tid] = tanhf(acc);
}

// ---- pass1: a1 = att_sigmoid(x.h1); partials of sum(a1*x); store a1 ----
__global__ void __launch_bounds__(256, 4) pass1_kernel(const float* __restrict__ x,
                                                       float* __restrict__ ws) {
    const float* h = ws + WS_H1;
    float* aA0 = ws + WS_A;
    float* aA1 = ws + WS_A + NROWS;
    float* part = ws + WS_P2;
    const int tid = threadIdx.x, lane = tid & 63, wv = tid >> 6;
    const int r0 = blockIdx.x * CHUNK + wv * 4;
    const float4* x4 = reinterpret_cast<const float4*>(x);
    const float4 h0v = reinterpret_cast<const float4*>(h)[lane];
    const float4 h1v = reinterpret_cast<const float4*>(h + D)[lane];
    float4 acc0 = make_float4(0.f, 0.f, 0.f, 0.f);
    float4 acc1 = make_float4(0.f, 0.f, 0.f, 0.f);
    const size_t base = (size_t)r0 * F4 + lane;
    float4 b0[4], b1[4], b2[4];
#pragma unroll
    for (int j = 0; j < 4; ++j) b0[j] = x4[base + j * F4];
#pragma unroll
    for (int j = 0; j < 4; ++j) b1[j] = x4[base + 16 * F4 + j * F4];
    for (int it = 0; it < ITERS; ++it) {
        if (it + 2 < ITERS) {
            const size_t nb = base + (size_t)(it + 2) * 16 * F4;
#pragma unroll
            for (int j = 0; j < 4; ++j) b2[j] = x4[nb + j * F4];
        }
        float d0[4], d1[4];
#pragma unroll
        for (int j = 0; j < 4; ++j) { d0[j] = dot4(b0[j], h0v); d1[j] = dot4(b0[j], h1v); }
#pragma unroll
        for (int j = 0; j < 4; ++j) { d0[j] = wave_sum(d0[j]); d1[j] = wave_sum(d1[j]); }
        float a0[4], a1[4];
#pragma unroll
        for (int j = 0; j < 4; ++j) {
            a0[j] = att_sigmoid(d0[j]);
            a1[j] = att_sigmoid(d1[j]);
            acc4(acc0, a0[j], b0[j]);
            acc4(acc1, a1[j], b0[j]);
        }
        const int rb = r0 + it * 16;
        if (lane == 0)
            *reinterpret_cast<float4*>(aA0 + rb) = make_float4(a0[0], a0[1], a0[2], a0[3]);
        else if (lane == 1)
            *reinterpret_cast<float4*>(aA1 + rb) = make_float4(a1[0], a1[1], a1[2], a1[3]);
#pragma unroll
        for (int j = 0; j < 4; ++j) { b0[j] = b1[j]; b1[j] = b2[j]; }
    }
    __shared__ float4 sh[2][256];
    sh[0][tid] = acc0;
    sh[1][tid] = acc1;
    __syncthreads();
    if (tid < 128) {
        int hh = tid >> 6;
        int t = tid & 63;
        float4 a = sh[hh][t], b = sh[hh][t + 64], c = sh[hh][t + 128], d = sh[hh][t + 192];
        float4 s;
        s.x = (a.x + b.x) + (c.x + d.x);
        s.y = (a.y + b.y) + (c.y + d.y);
        s.z = (a.z + b.z) + (c.z + d.z);
        s.w = (a.w + b.w) + (c.w + d.w);
        reinterpret_cast<float4*>(part)[blockIdx.x * 128 + tid] = s;
    }
}

// ---- pass2: a2 = att_sigmoid(a1*(x.h2)); partials of sum(a2*a1*x) ----
__global__ void __launch_bounds__(256, 4) pass2_kernel(const float* __restrict__ x,
                                                       float* __restrict__ ws) {
    const float* h = ws + WS_H2;
    const float* aA0 = ws + WS_A;
    const float* aA1 = ws + WS_A + NROWS;
    float* part = ws + WS_P2;
    const int tid = threadIdx.x, lane = tid & 63, wv = tid >> 6;
    const int r0 = blockIdx.x * CHUNK + wv * 4;
    const float4* x4 = reinterpret_cast<const float4*>(x);
    const float4 h0v = reinterpret_cast<const float4*>(h)[lane];
    const float4 h1v = reinterpret_cast<const float4*>(h + D)[lane];
    float4 acc0 = make_float4(0.f, 0.f, 0.f, 0.f);
    float4 acc1 = make_float4(0.f, 0.f, 0.f, 0.f);
    const size_t base = (size_t)r0 * F4 + lane;
    float4 b0[4], b1[4], b2[4];
    float4 aa0_0, aa1_0, aa0_1, aa1_1, aa0_2, aa1_2;
#pragma unroll
    for (int j = 0; j < 4; ++j) b0[j] = x4[base + j * F4];
    aa0_0 = *reinterpret_cast<const float4*>(aA0 + r0);
    aa1_0 = *reinterpret_cast<const float4*>(aA1 + r0);
#pragma unroll
    for (int j = 0; j < 4; ++j) b1[j] = x4[base + 16 * F4 + j * F4];
    aa0_1 = *reinterpret_cast<const float4*>(aA0 + r0 + 16);
    aa1_1 = *reinterpret_cast<const float4*>(aA1 + r0 + 16);
    for (int it = 0; it < ITERS; ++it) {
        if (it + 2 < ITERS) {
            const size_t nb = base + (size_t)(it + 2) * 16 * F4;
#pragma unroll
            for (int j = 0; j < 4; ++j) b2[j] = x4[nb + j * F4];
            aa0_2 = *reinterpret_cast<const float4*>(aA0 + r0 + (it + 2) * 16);
            aa1_2 = *reinterpret_cast<const float4*>(aA1 + r0 + (it + 2) * 16);
        }
        float d0[4], d1[4];
#pragma unroll
        for (int j = 0; j < 4; ++j) { d0[j] = dot4(b0[j], h0v); d1[j] = dot4(b0[j], h1v); }
#pragma unroll
        for (int j = 0; j < 4; ++j) { d0[j] = wave_sum(d0[j]); d1[j] = wave_sum(d1[j]); }
        float w0[4], w1[4];
        w0[0] = att_sigmoid(aa0_0.x * d0[0]) * aa0_0.x;
        w0[1] = att_sigmoid(aa0_0.y * d0[1]) * aa0_0.y;
        w0[2] = att_sigmoid(aa0_0.z * d0[2]) * aa0_0.z;
        w0[3] = att_sigmoid(aa0_0.w * d0[3]) * aa0_0.w;
        w1[0] = att_sigmoid(aa1_0.x * d1[0]) * aa1_0.x;
        w1[1] = att_sigmoid(aa1_0.y * d1[1]) * aa1_0.y;
        w1[2] = att_sigmoid(aa1_0.z * d1[2]) * aa1_0.z;
        w1[3] = att_sigmoid(aa1_0.w * d1[3]) * aa1_0.w;
#pragma unroll
        for (int j = 0; j < 4; ++j) {
            acc4(acc0, w0[j], b0[j]);
            acc4(acc1, w1[j], b0[j]);
        }
#pragma unroll
        for (int j = 0; j < 4; ++j) { b0[j] = b1[j]; b1[j] = b2[j]; }
        aa0_0 = aa0_1; aa0_1 = aa0_2;
        aa1_0 = aa1_1; aa1_1 = aa1_2;
    }
    __shared__ float4 sh[2][256];
    sh[0][tid] = acc0;
    sh[1][tid] = acc1;
    __syncthreads();
    if (tid < 128) {
        int hh = tid >> 6;
        int t = tid & 63;
        float4 a = sh[hh][t], b = sh[hh][t + 64], c = sh[hh][t + 128], d = sh[hh][t + 192];
        float4 s;
        s.x = (a.x + b.x) + (c.x + d.x);
        s.y = (a.y + b.y) + (c.y + d.y);
        s.z = (a.z + b.z) + (c.z + d.z);
        s.w = (a.w + b.w) + (c.w + d.w);
        reinterpret_cast<float4*>(part)[blockIdx.x * 128 + tid] = s;
    }
}

// ---- final: out[head*256+c] = sum over NBLK partial rows (direct store) ----
__global__ void __launch_bounds__(256) out_reduce(const float* __restrict__ part,
                                                  float* __restrict__ out) {
    const int head = blockIdx.x;
    const int tid = threadIdx.x, lane = tid & 63, wv = tid >> 6;
    const float4* p4 = reinterpret_cast<const float4*>(part) + head * 64 + lane;
    float4 s = make_float4(0.f, 0.f, 0.f, 0.f);
#pragma unroll 5
    for (int r = wv; r < NBLK; r += 4) {
        float4 v = p4[(size_t)r * 128];
        s.x += v.x; s.y += v.y; s.z += v.z; s.w += v.w;
    }
    __shared__ float4 red[4][64];
    red[wv][lane] = s;
    __syncthreads();
    if (tid < 64) {
        float4 a = red[0][tid], b = red[1][tid], c = red[2][tid], d = red[3][tid];
        float4 o;
        o.x = (a.x + b.x) + (c.x + d.x);
        o.y = (a.y + b.y) + (c.y + d.y);
        o.z = (a.z + b.z) + (c.z + d.z);
        o.w = (a.w + b.w) + (c.w + d.w);
        reinterpret_cast<float4*>(out)[head * 64 + tid] = o;
    }
}

extern "C" void kernel_launch(void* const* d_in, const int* in_sizes, int n_in,
                              void* d_out, int out_size, void* d_ws, size_t ws_size,
                              hipStream_t stream) {
    const float* x = (const float*)d_in[0];   // (200000, 256) f32
    const float* W = (const float*)d_in[1];   // (2, 256, 256) f32
    float* out = (float*)d_out;               // (1, 512) f32
    float* ws = (float*)d_ws;

    colsum_kernel<<<dim3(NBLK), dim3(256), 0, stream>>>(x, ws + WS_P1);
    hproj_fused<<<dim3(2), dim3(256), 0, stream>>>(W, ws + WS_P1, 64, 0, 1.0f / NROWS, ws + WS_H1);
    pass1_kernel<<<dim3(NBLK), dim3(256), 0, stream>>>(x, ws);
    hproj_fused<<<dim3(2), dim3(256), 0, stream>>>(W, ws + WS_P2, 128, 64, 1.0f / NROWS, ws + WS_H2);
    pass2_kernel<<<dim3(NBLK), dim3(256), 0, stream>>>(x, ws);
    out_reduce<<<dim3(2), dim3(256), 0, stream>>>(ws + WS_P2, out);
}